// Round 13
// baseline (317.481 us; speedup 1.0000x reference)
//
#include <hip/hip_runtime.h>
#include <stdint.h>

typedef __bf16 bf16_t;
typedef __bf16 bf16x8 __attribute__((ext_vector_type(8)));
typedef float f32x4 __attribute__((ext_vector_type(4)));
typedef float f32x16 __attribute__((ext_vector_type(16)));
typedef int i32x4 __attribute__((ext_vector_type(4)));
typedef int i32x8 __attribute__((ext_vector_type(8)));

typedef const __attribute__((address_space(1))) void gv_t;
typedef __attribute__((address_space(3))) void lv_t;

// =============================================================================
// Round 13:
//   PV    -> gemm8p32: same 4-phase split-K=2 schedule, MFMA switched to
//            32x32x16 bf16 (15% fewer matrix-pipe cycles, half the issue slots);
//            rowsum_recip folded into PV prologue (partial moved to ws).
//   QKV   -> gemm2p 256x128 2-phase (round 11, unchanged)
//   scores-> scores8p (unchanged since round 7; bitwise-identical S)
// NOTE (round-8 post-mortem): loop bodies inline — no reg-array-by-ref helpers.
// =============================================================================

template <int LDK>
__device__ __forceinline__ void stage_half2(const bf16_t* g, bf16_t* lh,
                                            int wave, int lane) {
#pragma unroll
  for (int i = 0; i < 2; ++i) {
    const int ub = i * 8192 + wave * 1024;
    const int o = ub + lane * 16;
    const int row = o >> 7;
    const int kb = (o & 127) ^ ((row & 7) << 4);
    const char* src = (const char*)g + (size_t)row * (LDK * 2) + kb;
    __builtin_amdgcn_global_load_lds((gv_t*)src, (lv_t*)(lh + (ub >> 1)), 16, 0, 0);
  }
}

__device__ __forceinline__ bf16x8 ld_frag2(const bf16_t* h, int r, int s, int lane) {
  int byte = r * 128 + s * 64 + ((lane >> 4) << 4);
  byte ^= (r & 7) << 4;
  return *(const bf16x8*)((const char*)h + byte);
}

// 32x32x16 A/B fragment: r = row within 128-row half (incl lane&31 component),
// ks = K-step (16 elems = 32 B). lane>>5 selects k 0-7 vs 8-15 (16 B).
__device__ __forceinline__ bf16x8 ld_frag32(const bf16_t* h, int r, int ks,
                                            int lane) {
  int byte = r * 128 + ks * 32 + ((lane >> 5) << 4);
  byte ^= (r & 7) << 4;
  return *(const bf16x8*)((const char*)h + byte);
}

// ============ PV: 256x256 4-phase split-K, 32x32x16 MFMA, fused rowsum =========
template <int NN, int KEXT, int LDK>
__global__ __launch_bounds__(512) void gemm8p32(
    const bf16_t* __restrict__ A, const bf16_t* __restrict__ Bt,
    float* __restrict__ Cf0, bf16_t* __restrict__ Cf1b,
    const float* __restrict__ partial) {
  __shared__ __align__(16) bf16_t L[2][4][8192];
  __shared__ float rl[256];

  const int tid = threadIdx.x;
  const int wave = tid >> 6;
  const int lane = tid & 63;

  const int bid = blockIdx.x;
  const int x = bid & 7;
  const int j = bid >> 3;
  // per XCD 4tm x 4tn x 2ks
  const int ks = j >> 4;
  const int tm = (x << 2) | (j & 3);
  const int tn = (j >> 2) & 3;

  // fused rowsum: r = 1/sum over the 32 column-tiles' partials for our 256 rows
  if (tid < 256) {
    float s = 0.f;
#pragma unroll
    for (int t = 0; t < 32; ++t) s += partial[(size_t)t * 8192 + tm * 256 + tid];
    rl[tid] = 1.0f / s;
  }
  __syncthreads();

  const bf16_t* Ab = A + (size_t)tm * (256 * LDK) + (size_t)ks * KEXT;
  const bf16_t* Bb = Bt + (size_t)tn * (256 * LDK) + (size_t)ks * KEXT;

  const int wr64 = (wave >> 2) * 64;
  const int wc32 = (wave & 3) * 32;
  constexpr int nt = KEXT >> 6;

  const f32x16 zz = {0.f, 0.f, 0.f, 0.f, 0.f, 0.f, 0.f, 0.f,
                     0.f, 0.f, 0.f, 0.f, 0.f, 0.f, 0.f, 0.f};
  f32x16 acc00[2], acc01[2], acc10[2], acc11[2];
#pragma unroll
  for (int mb = 0; mb < 2; ++mb) {
    acc00[mb] = zz;
    acc01[mb] = zz;
    acc10[mb] = zz;
    acc11[mb] = zz;
  }

  // Prologue (round-10 proven): tile0's 4 halves + {A0,B0,B1}(1); vmcnt(6).
  stage_half2<LDK>(Ab, &L[0][0][0], wave, lane);
  stage_half2<LDK>(Ab + (size_t)128 * LDK, &L[0][1][0], wave, lane);
  stage_half2<LDK>(Bb, &L[0][2][0], wave, lane);
  stage_half2<LDK>(Bb + (size_t)128 * LDK, &L[0][3][0], wave, lane);
  stage_half2<LDK>(Ab + 64, &L[1][0][0], wave, lane);
  stage_half2<LDK>(Bb + 64, &L[1][2][0], wave, lane);
  stage_half2<LDK>(Bb + (size_t)128 * LDK + 64, &L[1][3][0], wave, lane);
  asm volatile("s_waitcnt vmcnt(6)" ::: "memory");
  __builtin_amdgcn_s_barrier();

  bf16x8 a[2][4], bA[4], bB[4];
  const int ar = (lane & 31);

#pragma unroll 1
  for (int t = 0; t < nt; ++t) {
    const int cur = t & 1;
    const bf16_t* A0h = &L[cur][0][0];
    const bf16_t* A1h = &L[cur][1][0];
    const bf16_t* B0h = &L[cur][2][0];
    const bf16_t* B1h = &L[cur][3][0];

    // -- phase 1: quadrant (0,0); stage A1(t+1) -> buf[nxt]
#pragma unroll
    for (int mb = 0; mb < 2; ++mb)
#pragma unroll
      for (int k = 0; k < 4; ++k)
        a[mb][k] = ld_frag32(A0h, wr64 + mb * 32 + ar, k, lane);
#pragma unroll
    for (int k = 0; k < 4; ++k) bA[k] = ld_frag32(B0h, wc32 + ar, k, lane);
    if (t + 1 < nt)
      stage_half2<LDK>(Ab + (size_t)128 * LDK + (t + 1) * 64, &L[cur ^ 1][1][0],
                       wave, lane);
    __builtin_amdgcn_s_barrier();
    __builtin_amdgcn_s_setprio(1);
#pragma unroll
    for (int k = 0; k < 4; ++k)
#pragma unroll
      for (int mb = 0; mb < 2; ++mb)
        acc00[mb] = __builtin_amdgcn_mfma_f32_32x32x16_bf16(a[mb][k], bA[k],
                                                            acc00[mb], 0, 0, 0);
    __builtin_amdgcn_s_setprio(0);
    __builtin_amdgcn_s_barrier();

    // -- phase 2: quadrant (0,1); stage A0(t+2) -> buf[cur]
#pragma unroll
    for (int k = 0; k < 4; ++k) bB[k] = ld_frag32(B1h, wc32 + ar, k, lane);
    if (t + 2 < nt)
      stage_half2<LDK>(Ab + (t + 2) * 64, &L[cur][0][0], wave, lane);
    __builtin_amdgcn_s_barrier();
    __builtin_amdgcn_s_setprio(1);
#pragma unroll
    for (int k = 0; k < 4; ++k)
#pragma unroll
      for (int mb = 0; mb < 2; ++mb)
        acc01[mb] = __builtin_amdgcn_mfma_f32_32x32x16_bf16(a[mb][k], bB[k],
                                                            acc01[mb], 0, 0, 0);
    __builtin_amdgcn_s_setprio(0);
    __builtin_amdgcn_s_barrier();

    // -- phase 3: quadrant (1,1); stage B0(t+2) -> buf[cur]
#pragma unroll
    for (int mb = 0; mb < 2; ++mb)
#pragma unroll
      for (int k = 0; k < 4; ++k)
        a[mb][k] = ld_frag32(A1h, wr64 + mb * 32 + ar, k, lane);
    if (t + 2 < nt)
      stage_half2<LDK>(Bb + (t + 2) * 64, &L[cur][2][0], wave, lane);
    __builtin_amdgcn_s_barrier();
    __builtin_amdgcn_s_setprio(1);
#pragma unroll
    for (int k = 0; k < 4; ++k)
#pragma unroll
      for (int mb = 0; mb < 2; ++mb)
        acc11[mb] = __builtin_amdgcn_mfma_f32_32x32x16_bf16(a[mb][k], bB[k],
                                                            acc11[mb], 0, 0, 0);
    __builtin_amdgcn_s_setprio(0);
    __builtin_amdgcn_s_barrier();

    // -- phase 4: quadrant (1,0); stage B1(t+2) -> buf[cur]; boundary vmcnt(6)
    if (t + 2 < nt)
      stage_half2<LDK>(Bb + (size_t)128 * LDK + (t + 2) * 64, &L[cur][3][0],
                       wave, lane);
    __builtin_amdgcn_s_barrier();
    __builtin_amdgcn_s_setprio(1);
#pragma unroll
    for (int k = 0; k < 4; ++k)
#pragma unroll
      for (int mb = 0; mb < 2; ++mb)
        acc10[mb] = __builtin_amdgcn_mfma_f32_32x32x16_bf16(a[mb][k], bA[k],
                                                            acc10[mb], 0, 0, 0);
    __builtin_amdgcn_s_setprio(0);
    if (t + 2 < nt)
      asm volatile("s_waitcnt vmcnt(6)" ::: "memory");
    else
      asm volatile("s_waitcnt vmcnt(0)" ::: "memory");
    __builtin_amdgcn_s_barrier();
  }

  // Epilogue. 32x32 C/D mapping (m74/m101-verified):
  // col = lane&31, row = (reg&3) + 8*(reg>>2) + 4*(lane>>5), reg in [0,16).
  const int colb = tn * 256 + wc32 + (lane & 31);
  const int rsub = (lane >> 5) << 2;
#define STORE_QUAD32(ACC, QM, QN)                                                \
  _Pragma("unroll") for (int mb = 0; mb < 2; ++mb) {                             \
    _Pragma("unroll") for (int g = 0; g < 4; ++g) {                              \
      const int lrow = QM * 128 + wr64 + mb * 32 + g * 8 + rsub;                 \
      const int row = tm * 256 + lrow;                                           \
      const int col = QN * 128 + colb;                                           \
      const float4 rv = *(const float4*)&rl[lrow];                               \
      _Pragma("unroll") for (int jj = 0; jj < 4; ++jj) {                         \
        const float v = ACC[mb][g * 4 + jj] * ((const float*)&rv)[jj];           \
        if (ks == 0)                                                             \
          Cf0[(size_t)(row + jj) * NN + col] = v;                                \
        else                                                                     \
          Cf1b[(size_t)(row + jj) * NN + col] = (bf16_t)v;                       \
      }                                                                          \
    }                                                                            \
  }
  STORE_QUAD32(acc00, 0, 0)
  STORE_QUAD32(acc01, 0, 1)
  STORE_QUAD32(acc10, 1, 0)
  STORE_QUAD32(acc11, 1, 1)
#undef STORE_QUAD32
}

// ======================= QKV: 256x128 2-phase (round-11 form) ===================
template <int NN, int KEXT, int LDK>
__global__ __launch_bounds__(512) void gemm2p(
    const bf16_t* __restrict__ A, const bf16_t* __restrict__ Bt,
    uint8_t* __restrict__ qo, uint8_t* __restrict__ ko,
    bf16_t* __restrict__ vtb) {
  __shared__ __align__(16) bf16_t L[2][3][8192];  // [buf][A0,A1,B][128*64]

  const int tid = threadIdx.x;
  const int wave = tid >> 6;
  const int lane = tid & 63;

  const int bid = blockIdx.x;
  const int x = bid & 7;
  const int j = bid >> 3;
  const int tm = (x << 2) | (j & 3);  // 0..31
  const int tn = j >> 2;              // 0..NN/128-1

  const bf16_t* Ab = A + (size_t)tm * (256 * LDK);
  const bf16_t* Bb = Bt + (size_t)tn * (128 * LDK);

  const int wr64 = (wave >> 2) * 64;
  const int wc32 = (wave & 3) * 32;
  const int fr = lane & 15;
  constexpr int nt = KEXT >> 6;

  f32x4 acc0[4][2], acc1[4][2];
#pragma unroll
  for (int m = 0; m < 4; ++m)
#pragma unroll
    for (int n = 0; n < 2; ++n) {
      acc0[m][n] = (f32x4){0.f, 0.f, 0.f, 0.f};
      acc1[m][n] = (f32x4){0.f, 0.f, 0.f, 0.f};
    }

  stage_half2<LDK>(Ab, &L[0][0][0], wave, lane);
  stage_half2<LDK>(Ab + (size_t)128 * LDK, &L[0][1][0], wave, lane);
  stage_half2<LDK>(Bb, &L[0][2][0], wave, lane);
  stage_half2<LDK>(Ab + 64, &L[1][0][0], wave, lane);
  stage_half2<LDK>(Bb + 64, &L[1][2][0], wave, lane);
  asm volatile("s_waitcnt vmcnt(4)" ::: "memory");
  __builtin_amdgcn_s_barrier();

  bf16x8 a[4][2], b[2][2];

#pragma unroll 1
  for (int t = 0; t < nt; ++t) {
    const int cur = t & 1;
    const bf16_t* A0h = &L[cur][0][0];
    const bf16_t* A1h = &L[cur][1][0];
    const bf16_t* Bh = &L[cur][2][0];

    // -- phase 1: M-half 0; stage A1(t+1) -> buf[nxt]
#pragma unroll
    for (int m = 0; m < 4; ++m)
#pragma unroll
      for (int s = 0; s < 2; ++s)
        a[m][s] = ld_frag2(A0h, wr64 + m * 16 + fr, s, lane);
#pragma unroll
    for (int n = 0; n < 2; ++n)
#pragma unroll
      for (int s = 0; s < 2; ++s)
        b[n][s] = ld_frag2(Bh, wc32 + n * 16 + fr, s, lane);
    if (t + 1 < nt)
      stage_half2<LDK>(Ab + (size_t)128 * LDK + (t + 1) * 64, &L[cur ^ 1][1][0],
                       wave, lane);
    __builtin_amdgcn_s_barrier();
    __builtin_amdgcn_s_setprio(1);
#pragma unroll
    for (int s = 0; s < 2; ++s)
#pragma unroll
      for (int m = 0; m < 4; ++m)
#pragma unroll
        for (int n = 0; n < 2; ++n)
          acc0[m][n] = __builtin_amdgcn_mfma_f32_16x16x32_bf16(a[m][s], b[n][s],
                                                               acc0[m][n], 0, 0, 0);
    __builtin_amdgcn_s_setprio(0);
    __builtin_amdgcn_s_barrier();

    // -- phase 2: M-half 1; stage A0(t+2),B(t+2) -> buf[cur]; boundary vmcnt(4)
#pragma unroll
    for (int m = 0; m < 4; ++m)
#pragma unroll
      for (int s = 0; s < 2; ++s)
        a[m][s] = ld_frag2(A1h, wr64 + m * 16 + fr, s, lane);
    if (t + 2 < nt) {
      stage_half2<LDK>(Ab + (t + 2) * 64, &L[cur][0][0], wave, lane);
      stage_half2<LDK>(Bb + (t + 2) * 64, &L[cur][2][0], wave, lane);
    }
    __builtin_amdgcn_s_barrier();
    __builtin_amdgcn_s_setprio(1);
#pragma unroll
    for (int s = 0; s < 2; ++s)
#pragma unroll
      for (int m = 0; m < 4; ++m)
#pragma unroll
        for (int n = 0; n < 2; ++n)
          acc1[m][n] = __builtin_amdgcn_mfma_f32_16x16x32_bf16(a[m][s], b[n][s],
                                                               acc1[m][n], 0, 0, 0);
    __builtin_amdgcn_s_setprio(0);
    if (t + 2 < nt)
      asm volatile("s_waitcnt vmcnt(4)" ::: "memory");
    else
      asm volatile("s_waitcnt vmcnt(0)" ::: "memory");
    __builtin_amdgcn_s_barrier();
  }

  const int fro = (lane >> 4) * 4;
#define STORE_HALF(ACC, QM)                                                      \
  _Pragma("unroll") for (int m = 0; m < 4; ++m) {                                \
    _Pragma("unroll") for (int n = 0; n < 2; ++n) {                              \
      const int row = tm * 256 + QM * 128 + wr64 + m * 16 + fro;                 \
      const int col = tn * 128 + wc32 + n * 16 + fr;                             \
      if (col < 1024) {                                                          \
        _Pragma("unroll") for (int jj = 0; jj < 4; ++jj) {                       \
          int pk = __builtin_amdgcn_cvt_pk_fp8_f32(ACC[m][n][jj],                \
                                                   ACC[m][n][jj], 0, false);     \
          qo[(size_t)(row + jj) * 1024 + col] = (uint8_t)pk;                     \
        }                                                                        \
      } else if (col < 2048) {                                                   \
        _Pragma("unroll") for (int jj = 0; jj < 4; ++jj) {                       \
          int pk = __builtin_amdgcn_cvt_pk_fp8_f32(ACC[m][n][jj],                \
                                                   ACC[m][n][jj], 0, false);     \
          ko[(size_t)(row + jj) * 1024 + (col - 1024)] = (uint8_t)pk;            \
        }                                                                        \
      } else {                                                                   \
        union { bf16_t h[4]; uint2 u; } tpk;                                     \
        _Pragma("unroll") for (int jj = 0; jj < 4; ++jj)                         \
            tpk.h[jj] = (bf16_t)ACC[m][n][jj];                                   \
        *(uint2*)&vtb[(size_t)(col - 2048) * 8192 + row] = tpk.u;                \
      }                                                                          \
    }                                                                            \
  }
  STORE_HALF(acc0, 0)
  STORE_HALF(acc1, 1)
#undef STORE_HALF
}

// ============== MX-fp8 scores GEMM, 256^2 tile, 8-wave 4-phase cadence ===========
// Round-7 form — unchanged. K accumulation order identical -> bitwise-identical S.

__device__ __forceinline__ void stage_half8(const uint8_t* g, uint8_t* lh,
                                            int wave, int lane) {
#pragma unroll
  for (int i = 0; i < 2; ++i) {
    const int ub = i * 8192 + wave * 1024;
    const int o = ub + lane * 16;
    const int row = o >> 7;
    const int col = (o & 127) ^ ((row & 7) << 4);
    __builtin_amdgcn_global_load_lds((gv_t*)(g + (size_t)row * 1024 + col),
                                     (lv_t*)(lh + ub), 16, 0, 0);
  }
}

__device__ __forceinline__ i32x8 ld_frag8h(const uint8_t* h, int r, int lane) {
  const int sw = (r & 7) << 4;
  const int kg = (lane >> 4) * 32;
  const uint8_t* b = h + r * 128;
  i32x4 lo = *(const i32x4*)(b + (kg ^ sw));
  i32x4 hi = *(const i32x4*)(b + ((kg ^ sw) ^ 16));
  i32x8 v;
  v[0] = lo[0]; v[1] = lo[1]; v[2] = lo[2]; v[3] = lo[3];
  v[4] = hi[0]; v[5] = hi[1]; v[6] = hi[2]; v[7] = hi[3];
  return v;
}

__global__ __launch_bounds__(512) void scores8p(
    const uint8_t* __restrict__ qf, const uint8_t* __restrict__ kf,
    bf16_t* __restrict__ S, float* __restrict__ partial) {
  __shared__ __align__(16) uint8_t L[2][4][16384];

  const int tid = threadIdx.x;
  const int wave = tid >> 6;
  const int lane = tid & 63;

  const int bid = blockIdx.x;
  const int x = bid & 7;
  const int j = bid >> 3;
  const int tm = (x << 2) | (j & 3);  // 0..31
  const int tn = j >> 2;              // 0..31

  const uint8_t* Ab = qf + (size_t)tm * 256 * 1024;
  const uint8_t* Bb = kf + (size_t)tn * 256 * 1024;

  const int wr64 = (wave >> 2) * 64;
  const int wc32 = (wave & 3) * 32;
  const int fr = lane & 15;
  constexpr int nt = 8;  // 1024 / 128

  f32x4 acc00[4][2], acc01[4][2], acc10[4][2], acc11[4][2];
#pragma unroll
  for (int m = 0; m < 4; ++m)
#pragma unroll
    for (int n = 0; n < 2; ++n) {
      acc00[m][n] = (f32x4){0.f, 0.f, 0.f, 0.f};
      acc01[m][n] = (f32x4){0.f, 0.f, 0.f, 0.f};
      acc10[m][n] = (f32x4){0.f, 0.f, 0.f, 0.f};
      acc11[m][n] = (f32x4){0.f, 0.f, 0.f, 0.f};
    }

  stage_half8(Ab, &L[0][0][0], wave, lane);
  stage_half8(Ab + (size_t)128 * 1024, &L[0][1][0], wave, lane);
  stage_half8(Bb, &L[0][2][0], wave, lane);
  stage_half8(Bb + (size_t)128 * 1024, &L[0][3][0], wave, lane);
  stage_half8(Ab + 128, &L[1][0][0], wave, lane);
  stage_half8(Bb + (size_t)128 * 1024 + 128, &L[1][3][0], wave, lane);
  asm volatile("s_waitcnt vmcnt(4)" ::: "memory");
  __builtin_amdgcn_s_barrier();

  i32x8 a[4], bA[2], bB[2];

#pragma unroll 1
  for (int t = 0; t < nt; ++t) {
    const int cur = t & 1;
    const uint8_t* A0h = &L[cur][0][0];
    const uint8_t* A1h = &L[cur][1][0];
    const uint8_t* B0h = &L[cur][2][0];
    const uint8_t* B1h = &L[cur][3][0];

    // -- phase 1: quadrant (0,0); stage A1(t+1)
#pragma unroll
    for (int m = 0; m < 4; ++m) a[m] = ld_frag8h(A0h, wr64 + m * 16 + fr, lane);
#pragma unroll
    for (int n = 0; n < 2; ++n) bA[n] = ld_frag8h(B0h, wc32 + n * 16 + fr, lane);
    if (t + 1 < nt)
      stage_half8(Ab + (size_t)128 * 1024 + (t + 1) * 128, &L[cur ^ 1][1][0],
                  wave, lane);
    __builtin_amdgcn_s_barrier();
    __builtin_amdgcn_s_setprio(1);
#pragma unroll
    for (int m = 0; m < 4; ++m)
#pragma unroll
      for (int n = 0; n < 2; ++n)
        acc00[m][n] = __builtin_amdgcn_mfma_scale_f32_16x16x128_f8f6f4(
            a[m], bA[n], acc00[m][n], 0, 0, 0, 0x7F7F7F7F, 0, 0x7F7F7F7F);
    __builtin_amdgcn_s_setprio(0);
    __builtin_amdgcn_s_barrier();

    // -- phase 2: quadrant (0,1); stage B0(t+1)
#pragma unroll
    for (int n = 0; n < 2; ++n) bB[n] = ld_frag8h(B1h, wc32 + n * 16 + fr, lane);
    if (t + 1 < nt)
      stage_half8(Bb + (t + 1) * 128, &L[cur ^ 1][2][0], wave, lane);
    __builtin_amdgcn_s_barrier();
    __builtin_amdgcn_s_setprio(1);
#pragma unroll
    for (int m = 0; m < 4; ++m)
#pragma unroll
      for (int n = 0; n < 2; ++n)
        acc01[m][n] = __builtin_amdgcn_mfma_scale_f32_16x16x128_f8f6f4(
            a[m], bB[n], acc01[m][n], 0, 0, 0, 0x7F7F7F7F, 0, 0x7F7F7F7F);
    __builtin_amdgcn_s_setprio(0);
    __builtin_amdgcn_s_barrier();

    // -- phase 3: quadrant (1,1); stage A0(t+2)
#pragma unroll
    for (int m = 0; m < 4; ++m) a[m] = ld_frag8h(A1h, wr64 + m * 16 + fr, lane);
    if (t + 2 < nt)
      stage_half8(Ab + (t + 2) * 128, &L[cur][0][0], wave, lane);
    __builtin_amdgcn_s_barrier();
    __builtin_amdgcn_s_setprio(1);
#pragma unroll
    for (int m = 0; m < 4; ++m)
#pragma unroll
      for (int n = 0; n < 2; ++n)
        acc11[m][n] = __builtin_amdgcn_mfma_scale_f32_16x16x128_f8f6f4(
            a[m], bB[n], acc11[m][n], 0, 0, 0, 0x7F7F7F7F, 0, 0x7F7F7F7F);
    __builtin_amdgcn_s_setprio(0);
    __builtin_amdgcn_s_barrier();

    // -- phase 4: quadrant (1,0); stage B1(t+2); boundary counted-vmcnt
    if (t + 2 < nt)
      stage_half8(Bb + (size_t)128 * 1024 + (t + 2) * 128, &L[cur][3][0],
                  wave, lane);
    __builtin_amdgcn_s_barrier();
    __builtin_amdgcn_s_setprio(1);
#pragma unroll
    for (int m = 0; m < 4; ++m)
#pragma unroll
      for (int n = 0; n < 2; ++n)
        acc10[m][n] = __builtin_amdgcn_mfma_scale_f32_16x16x128_f8f6f4(
            a[m], bA[n], acc10[m][n], 0, 0, 0, 0x7F7F7F7F, 0, 0x7F7F7F7F);
    __builtin_amdgcn_s_setprio(0);
    if (t + 2 < nt)
      asm volatile("s_waitcnt vmcnt(4)" ::: "memory");
    else
      asm volatile("s_waitcnt vmcnt(0)" ::: "memory");
    __builtin_amdgcn_s_barrier();
  }

  // Epilogue: exp, bf16 store, per-row partial sums (verified rounds 4-12).
  const int fro = (lane >> 4) * 4;
#define EXPSTORE(ACC, QM, QN)                                                    \
  _Pragma("unroll") for (int m = 0; m < 4; ++m)                                  \
  _Pragma("unroll") for (int n = 0; n < 2; ++n)                                  \
  _Pragma("unroll") for (int jj = 0; jj < 4; ++jj) {                             \
    float e = __expf(ACC[m][n][jj]);                                             \
    ACC[m][n][jj] = e;                                                           \
    const int row = tm * 256 + QM * 128 + wr64 + m * 16 + fro + jj;              \
    const int col = tn * 256 + QN * 128 + wc32 + n * 16 + fr;                    \
    S[(size_t)row * 8192 + col] = (bf16_t)e;                                     \
  }
  EXPSTORE(acc00, 0, 0)
  EXPSTORE(acc01, 0, 1)
  EXPSTORE(acc10, 1, 0)
  EXPSTORE(acc11, 1, 1)
#undef EXPSTORE
  float* lsum = (float*)&L[0][0][0];  // 4 KB, LDS dead after K-loop
#define ROWSUM(A0, A1, QM)                                                       \
  _Pragma("unroll") for (int m = 0; m < 4; ++m) {                                \
    _Pragma("unroll") for (int jj = 0; jj < 4; ++jj) {                           \
      float s = A0[m][0][jj] + A0[m][1][jj] + A1[m][0][jj] + A1[m][1][jj];       \
      s += __shfl_xor(s, 1, 64);                                                 \
      s += __shfl_xor(s, 2, 64);                                                 \
      s += __shfl_xor(s, 4, 64);                                                 \
      s += __shfl_xor(s, 8, 64);                                                 \
      if (fr == 0) {                                                             \
        const int rl = QM * 128 + wr64 + m * 16 + fro + jj;                      \
        lsum[rl * 4 + (wave & 3)] = s;                                           \
      }                                                                          \
    }                                                                            \
  }
  ROWSUM(acc00, acc01, 0)
  ROWSUM(acc10, acc11, 1)
#undef ROWSUM
  __syncthreads();
  if (tid < 256) {
    float s = lsum[tid * 4] + lsum[tid * 4 + 1] + lsum[tid * 4 + 2] +
              lsum[tid * 4 + 3];
    partial[(size_t)tn * 8192 + tm * 256 + tid] = s;
  }
}

// ======================= fused convert, add =======================
__global__ __launch_bounds__(256) void cvt_fused(const float* __restrict__ x,
                                                 const float* __restrict__ wq,
                                                 const float* __restrict__ wk,
                                                 const float* __restrict__ wv,
                                                 bf16_t* __restrict__ dst,
                                                 float sq) {
  constexpr int NX = 8192 * 1024 / 8;  // x groups of 8
  constexpr int NW = 1024 * 1024 / 8;  // each W's groups of 8
  const int i = blockIdx.x * 256 + threadIdx.x;
  const float* s;
  int k = i;
  float scale;
  if (i < NX) {
    s = x; scale = 1.0f;
  } else if (i < NX + NW) {
    s = wq; k = i - NX; scale = sq;
  } else if (i < NX + 2 * NW) {
    s = wk; k = i - NX - NW; scale = sq;
  } else {
    s = wv; k = i - NX - 2 * NW; scale = 1.0f;
  }
  const float4* sp = (const float4*)s + (size_t)k * 2;
  float4 x0 = sp[0], x1 = sp[1];
  bf16x8 o;
  o[0] = (bf16_t)(x0.x * scale);
  o[1] = (bf16_t)(x0.y * scale);
  o[2] = (bf16_t)(x0.z * scale);
  o[3] = (bf16_t)(x0.w * scale);
  o[4] = (bf16_t)(x1.x * scale);
  o[5] = (bf16_t)(x1.y * scale);
  o[6] = (bf16_t)(x1.z * scale);
  o[7] = (bf16_t)(x1.w * scale);
  ((bf16x8*)dst)[i] = o;
}

__global__ __launch_bounds__(256) void add_p1(float* __restrict__ out,
                                              const bf16_t* __restrict__ p1b) {
  size_t i = (size_t)blockIdx.x * 256 + threadIdx.x;
  bf16x8 b = ((const bf16x8*)p1b)[i];
  float4 a0 = ((const float4*)out)[i * 2];
  float4 a1 = ((const float4*)out)[i * 2 + 1];
  a0.x += (float)b[0];
  a0.y += (float)b[1];
  a0.z += (float)b[2];
  a0.w += (float)b[3];
  a1.x += (float)b[4];
  a1.y += (float)b[5];
  a1.z += (float)b[6];
  a1.w += (float)b[7];
  ((float4*)out)[i * 2] = a0;
  ((float4*)out)[i * 2 + 1] = a1;
}

extern "C" void kernel_launch(void* const* d_in, const int* in_sizes, int n_in,
                              void* d_out, int out_size, void* d_ws, size_t ws_size,
                              hipStream_t stream) {
  const int N = 8192, D = 1024;
  const float* x = (const float*)d_in[0];
  const float* Wq = (const float*)d_in[1];
  const float* Wk = (const float*)d_in[2];
  const float* Wv = (const float*)d_in[3];
  float* out = (float*)d_out;

  // Workspace layout:
  //   [0,8)    qf  fp8 [8192,1024]   } after scores: P1b bf16 [8192,1024] (16 MB)
  //   [8,16)   kf  fp8 [8192,1024]   }
  //   [16,32)  vt  bf16 [1024,8192]  (V^T)
  //   [32,160) S   bf16 [8192,8192]  (exp'd, unnormalized)
  //   [160,161) partial f32 [32][8192] (1 MB; moved out of d_out so PV can
  //             read it concurrently with writing out)
  //   xb (16 MB) + Wb (6 MB) alias the start of S (dead before S written)
  uint8_t* qf = (uint8_t*)d_ws;
  uint8_t* kf = qf + (size_t)N * D;
  bf16_t* vt = (bf16_t*)(kf + (size_t)N * D);
  bf16_t* S = vt + (size_t)N * D;
  bf16_t* xb = S;
  bf16_t* P1b = (bf16_t*)d_ws;
  float* partial = (float*)(S + (size_t)N * N);

  const float sq = 0.1767766953f;  // 1/sqrt(32); folded into both Wq and Wk

  // 1) fused fp32 -> bf16 convert (x ++ Wq ++ Wk ++ Wv -> xb ++ Wb, contiguous)
  const int ncv = (N * D + 3 * D * D) / 8;
  cvt_fused<<<ncv / 256, 256, 0, stream>>>(x, Wq, Wk, Wv, xb, sq);

  // 2) fused QKV (256x128 2-phase, 768 blocks): q,k -> fp8; v -> vt bf16 (V^T)
  gemm2p<3072, 1024, 1024><<<(N / 256) * (3 * D / 128), 512, 0, stream>>>(
      xb, xb + (size_t)N * D, qf, kf, vt);

  // 3) scores (MX-fp8, 256^2 8-phase): S = exp(q·k) + partial row sums
  scores8p<<<(N / 256) * (N / 256), 512, 0, stream>>>(qf, kf, S, partial);

  // 4) out = (S @ vt^T) * r, 32x32-MFMA 4-phase split-K=2 with fused rowsum:
  //    ks0 -> out, ks1 -> P1b
  gemm8p32<1024, 4096, 8192><<<(N / 256) * (D / 256) * 2, 512, 0, stream>>>(
      S, vt, out, P1b, partial);

  // 5) out += P1b
  add_p1<<<(N * D / 8) / 256, 256, 0, stream>>>(out, P1b);
}

// Round 14
// 299.977 us; speedup vs baseline: 1.0584x; 1.0584x over previous
//
#include <hip/hip_runtime.h>
#include <stdint.h>

typedef __bf16 bf16_t;
typedef __bf16 bf16x8 __attribute__((ext_vector_type(8)));
typedef float f32x4 __attribute__((ext_vector_type(4)));
typedef int i32x4 __attribute__((ext_vector_type(4)));
typedef int i32x8 __attribute__((ext_vector_type(8)));

typedef const __attribute__((address_space(1))) void gv_t;
typedef __attribute__((address_space(3))) void lv_t;

// =============================================================================
// Round 14: revert PV to round-12 gemm8p (16x16 MFMA, 0 bank conflicts),
// keep round-13's fused-rowsum prologue (drops the rowsum_recip launch).
//   QKV   -> gemm2p 256x128 2-phase (round 11)
//   PV    -> gemm8p 256x256 4-phase split-K=2 + fused rowsum + add_p1
//   scores-> scores8p (unchanged since round 7; bitwise-identical S)
// LESSONS: (r8) no reg-array-by-ref helpers (scratch spills);
//          (r13) 32x32 MFMA frags are bank-conflicted under the (row&7)<<4
//          slot swizzle — slot permutation period is 8, 32 rows alias 4x.
// =============================================================================

template <int LDK>
__device__ __forceinline__ void stage_half2(const bf16_t* g, bf16_t* lh,
                                            int wave, int lane) {
#pragma unroll
  for (int i = 0; i < 2; ++i) {
    const int ub = i * 8192 + wave * 1024;
    const int o = ub + lane * 16;
    const int row = o >> 7;
    const int kb = (o & 127) ^ ((row & 7) << 4);
    const char* src = (const char*)g + (size_t)row * (LDK * 2) + kb;
    __builtin_amdgcn_global_load_lds((gv_t*)src, (lv_t*)(lh + (ub >> 1)), 16, 0, 0);
  }
}

__device__ __forceinline__ bf16x8 ld_frag2(const bf16_t* h, int r, int s, int lane) {
  int byte = r * 128 + s * 64 + ((lane >> 4) << 4);
  byte ^= (r & 7) << 4;
  return *(const bf16x8*)((const char*)h + byte);
}

// ============ PV: 256x256 4-phase split-K, 16x16 MFMA, fused rowsum ============
template <int NN, int KEXT, int LDK>
__global__ __launch_bounds__(512) void gemm8p(
    const bf16_t* __restrict__ A, const bf16_t* __restrict__ Bt,
    float* __restrict__ Cf0, bf16_t* __restrict__ Cf1b,
    const float* __restrict__ partial) {
  __shared__ __align__(16) bf16_t L[2][4][8192];
  __shared__ float rl[256];

  const int tid = threadIdx.x;
  const int wave = tid >> 6;
  const int lane = tid & 63;

  const int bid = blockIdx.x;
  const int x = bid & 7;
  const int j = bid >> 3;
  // per XCD 4tm x 4tn x 2ks
  const int ks = j >> 4;
  const int tm = (x << 2) | (j & 3);
  const int tn = (j >> 2) & 3;

  // fused rowsum: rl = 1/sum over the 32 column-tiles' partials for our 256 rows
  if (tid < 256) {
    float s = 0.f;
#pragma unroll
    for (int t = 0; t < 32; ++t) s += partial[(size_t)t * 8192 + tm * 256 + tid];
    rl[tid] = 1.0f / s;
  }
  __syncthreads();

  const bf16_t* Ab = A + (size_t)tm * (256 * LDK) + (size_t)ks * KEXT;
  const bf16_t* Bb = Bt + (size_t)tn * (256 * LDK) + (size_t)ks * KEXT;

  const int wr64 = (wave >> 2) * 64;
  const int wc32 = (wave & 3) * 32;
  const int fr = lane & 15;
  constexpr int nt = KEXT >> 6;

  f32x4 acc00[4][2], acc01[4][2], acc10[4][2], acc11[4][2];
#pragma unroll
  for (int m = 0; m < 4; ++m)
#pragma unroll
    for (int n = 0; n < 2; ++n) {
      acc00[m][n] = (f32x4){0.f, 0.f, 0.f, 0.f};
      acc01[m][n] = (f32x4){0.f, 0.f, 0.f, 0.f};
      acc10[m][n] = (f32x4){0.f, 0.f, 0.f, 0.f};
      acc11[m][n] = (f32x4){0.f, 0.f, 0.f, 0.f};
    }

  // Prologue (round-10 proven): tile0's 4 halves + {A0,B0,B1}(1); vmcnt(6).
  stage_half2<LDK>(Ab, &L[0][0][0], wave, lane);
  stage_half2<LDK>(Ab + (size_t)128 * LDK, &L[0][1][0], wave, lane);
  stage_half2<LDK>(Bb, &L[0][2][0], wave, lane);
  stage_half2<LDK>(Bb + (size_t)128 * LDK, &L[0][3][0], wave, lane);
  stage_half2<LDK>(Ab + 64, &L[1][0][0], wave, lane);
  stage_half2<LDK>(Bb + 64, &L[1][2][0], wave, lane);
  stage_half2<LDK>(Bb + (size_t)128 * LDK + 64, &L[1][3][0], wave, lane);
  asm volatile("s_waitcnt vmcnt(6)" ::: "memory");
  __builtin_amdgcn_s_barrier();

  bf16x8 a[4][2], bA[2][2], bB[2][2];

#pragma unroll 1
  for (int t = 0; t < nt; ++t) {
    const int cur = t & 1;
    const bf16_t* A0h = &L[cur][0][0];
    const bf16_t* A1h = &L[cur][1][0];
    const bf16_t* B0h = &L[cur][2][0];
    const bf16_t* B1h = &L[cur][3][0];

    // -- phase 1: quadrant (0,0); stage A1(t+1) -> buf[nxt]
#pragma unroll
    for (int m = 0; m < 4; ++m)
#pragma unroll
      for (int s = 0; s < 2; ++s)
        a[m][s] = ld_frag2(A0h, wr64 + m * 16 + fr, s, lane);
#pragma unroll
    for (int n = 0; n < 2; ++n)
#pragma unroll
      for (int s = 0; s < 2; ++s)
        bA[n][s] = ld_frag2(B0h, wc32 + n * 16 + fr, s, lane);
    if (t + 1 < nt)
      stage_half2<LDK>(Ab + (size_t)128 * LDK + (t + 1) * 64, &L[cur ^ 1][1][0],
                       wave, lane);
    __builtin_amdgcn_s_barrier();
    __builtin_amdgcn_s_setprio(1);
#pragma unroll
    for (int s = 0; s < 2; ++s)
#pragma unroll
      for (int m = 0; m < 4; ++m)
#pragma unroll
        for (int n = 0; n < 2; ++n)
          acc00[m][n] = __builtin_amdgcn_mfma_f32_16x16x32_bf16(a[m][s], bA[n][s],
                                                                acc00[m][n], 0, 0, 0);
    __builtin_amdgcn_s_setprio(0);
    __builtin_amdgcn_s_barrier();

    // -- phase 2: quadrant (0,1); stage A0(t+2) -> buf[cur]
#pragma unroll
    for (int n = 0; n < 2; ++n)
#pragma unroll
      for (int s = 0; s < 2; ++s)
        bB[n][s] = ld_frag2(B1h, wc32 + n * 16 + fr, s, lane);
    if (t + 2 < nt)
      stage_half2<LDK>(Ab + (t + 2) * 64, &L[cur][0][0], wave, lane);
    __builtin_amdgcn_s_barrier();
    __builtin_amdgcn_s_setprio(1);
#pragma unroll
    for (int s = 0; s < 2; ++s)
#pragma unroll
      for (int m = 0; m < 4; ++m)
#pragma unroll
        for (int n = 0; n < 2; ++n)
          acc01[m][n] = __builtin_amdgcn_mfma_f32_16x16x32_bf16(a[m][s], bB[n][s],
                                                                acc01[m][n], 0, 0, 0);
    __builtin_amdgcn_s_setprio(0);
    __builtin_amdgcn_s_barrier();

    // -- phase 3: quadrant (1,1); stage B0(t+2) -> buf[cur]
#pragma unroll
    for (int m = 0; m < 4; ++m)
#pragma unroll
      for (int s = 0; s < 2; ++s)
        a[m][s] = ld_frag2(A1h, wr64 + m * 16 + fr, s, lane);
    if (t + 2 < nt)
      stage_half2<LDK>(Bb + (t + 2) * 64, &L[cur][2][0], wave, lane);
    __builtin_amdgcn_s_barrier();
    __builtin_amdgcn_s_setprio(1);
#pragma unroll
    for (int s = 0; s < 2; ++s)
#pragma unroll
      for (int m = 0; m < 4; ++m)
#pragma unroll
        for (int n = 0; n < 2; ++n)
          acc11[m][n] = __builtin_amdgcn_mfma_f32_16x16x32_bf16(a[m][s], bB[n][s],
                                                                acc11[m][n], 0, 0, 0);
    __builtin_amdgcn_s_setprio(0);
    __builtin_amdgcn_s_barrier();

    // -- phase 4: quadrant (1,0); stage B1(t+2) -> buf[cur]; boundary vmcnt(6)
    if (t + 2 < nt)
      stage_half2<LDK>(Bb + (size_t)128 * LDK + (t + 2) * 64, &L[cur][3][0],
                       wave, lane);
    __builtin_amdgcn_s_barrier();
    __builtin_amdgcn_s_setprio(1);
#pragma unroll
    for (int s = 0; s < 2; ++s)
#pragma unroll
      for (int m = 0; m < 4; ++m)
#pragma unroll
        for (int n = 0; n < 2; ++n)
          acc10[m][n] = __builtin_amdgcn_mfma_f32_16x16x32_bf16(a[m][s], bA[n][s],
                                                                acc10[m][n], 0, 0, 0);
    __builtin_amdgcn_s_setprio(0);
    if (t + 2 < nt)
      asm volatile("s_waitcnt vmcnt(6)" ::: "memory");
    else
      asm volatile("s_waitcnt vmcnt(0)" ::: "memory");
    __builtin_amdgcn_s_barrier();
  }

  const int fro = (lane >> 4) * 4;
#define STORE_QUAD(ACC, QM, QN)                                                  \
  _Pragma("unroll") for (int m = 0; m < 4; ++m) {                                \
    _Pragma("unroll") for (int n = 0; n < 2; ++n) {                              \
      const int lrow = QM * 128 + wr64 + m * 16 + fro;                           \
      const int row = tm * 256 + lrow;                                           \
      const int col = tn * 256 + QN * 128 + wc32 + n * 16 + fr;                  \
      const float4 rv = *(const float4*)&rl[lrow];                               \
      if (ks == 0) {                                                             \
        _Pragma("unroll") for (int jj = 0; jj < 4; ++jj)                         \
            Cf0[(size_t)(row + jj) * NN + col] =                                 \
                ACC[m][n][jj] * ((const float*)&rv)[jj];                         \
      } else {                                                                   \
        _Pragma("unroll") for (int jj = 0; jj < 4; ++jj)                         \
            Cf1b[(size_t)(row + jj) * NN + col] =                                \
                (bf16_t)(ACC[m][n][jj] * ((const float*)&rv)[jj]);               \
      }                                                                          \
    }                                                                            \
  }
  STORE_QUAD(acc00, 0, 0)
  STORE_QUAD(acc01, 0, 1)
  STORE_QUAD(acc10, 1, 0)
  STORE_QUAD(acc11, 1, 1)
#undef STORE_QUAD
}

// ======================= QKV: 256x128 2-phase (round-11 form) ===================
template <int NN, int KEXT, int LDK>
__global__ __launch_bounds__(512) void gemm2p(
    const bf16_t* __restrict__ A, const bf16_t* __restrict__ Bt,
    uint8_t* __restrict__ qo, uint8_t* __restrict__ ko,
    bf16_t* __restrict__ vtb) {
  __shared__ __align__(16) bf16_t L[2][3][8192];  // [buf][A0,A1,B][128*64]

  const int tid = threadIdx.x;
  const int wave = tid >> 6;
  const int lane = tid & 63;

  const int bid = blockIdx.x;
  const int x = bid & 7;
  const int j = bid >> 3;
  const int tm = (x << 2) | (j & 3);  // 0..31
  const int tn = j >> 2;              // 0..NN/128-1

  const bf16_t* Ab = A + (size_t)tm * (256 * LDK);
  const bf16_t* Bb = Bt + (size_t)tn * (128 * LDK);

  const int wr64 = (wave >> 2) * 64;
  const int wc32 = (wave & 3) * 32;
  const int fr = lane & 15;
  constexpr int nt = KEXT >> 6;

  f32x4 acc0[4][2], acc1[4][2];
#pragma unroll
  for (int m = 0; m < 4; ++m)
#pragma unroll
    for (int n = 0; n < 2; ++n) {
      acc0[m][n] = (f32x4){0.f, 0.f, 0.f, 0.f};
      acc1[m][n] = (f32x4){0.f, 0.f, 0.f, 0.f};
    }

  stage_half2<LDK>(Ab, &L[0][0][0], wave, lane);
  stage_half2<LDK>(Ab + (size_t)128 * LDK, &L[0][1][0], wave, lane);
  stage_half2<LDK>(Bb, &L[0][2][0], wave, lane);
  stage_half2<LDK>(Ab + 64, &L[1][0][0], wave, lane);
  stage_half2<LDK>(Bb + 64, &L[1][2][0], wave, lane);
  asm volatile("s_waitcnt vmcnt(4)" ::: "memory");
  __builtin_amdgcn_s_barrier();

  bf16x8 a[4][2], b[2][2];

#pragma unroll 1
  for (int t = 0; t < nt; ++t) {
    const int cur = t & 1;
    const bf16_t* A0h = &L[cur][0][0];
    const bf16_t* A1h = &L[cur][1][0];
    const bf16_t* Bh = &L[cur][2][0];

    // -- phase 1: M-half 0; stage A1(t+1) -> buf[nxt]
#pragma unroll
    for (int m = 0; m < 4; ++m)
#pragma unroll
      for (int s = 0; s < 2; ++s)
        a[m][s] = ld_frag2(A0h, wr64 + m * 16 + fr, s, lane);
#pragma unroll
    for (int n = 0; n < 2; ++n)
#pragma unroll
      for (int s = 0; s < 2; ++s)
        b[n][s] = ld_frag2(Bh, wc32 + n * 16 + fr, s, lane);
    if (t + 1 < nt)
      stage_half2<LDK>(Ab + (size_t)128 * LDK + (t + 1) * 64, &L[cur ^ 1][1][0],
                       wave, lane);
    __builtin_amdgcn_s_barrier();
    __builtin_amdgcn_s_setprio(1);
#pragma unroll
    for (int s = 0; s < 2; ++s)
#pragma unroll
      for (int m = 0; m < 4; ++m)
#pragma unroll
        for (int n = 0; n < 2; ++n)
          acc0[m][n] = __builtin_amdgcn_mfma_f32_16x16x32_bf16(a[m][s], b[n][s],
                                                               acc0[m][n], 0, 0, 0);
    __builtin_amdgcn_s_setprio(0);
    __builtin_amdgcn_s_barrier();

    // -- phase 2: M-half 1; stage A0(t+2),B(t+2) -> buf[cur]; boundary vmcnt(4)
#pragma unroll
    for (int m = 0; m < 4; ++m)
#pragma unroll
      for (int s = 0; s < 2; ++s)
        a[m][s] = ld_frag2(A1h, wr64 + m * 16 + fr, s, lane);
    if (t + 2 < nt) {
      stage_half2<LDK>(Ab + (t + 2) * 64, &L[cur][0][0], wave, lane);
      stage_half2<LDK>(Bb + (t + 2) * 64, &L[cur][2][0], wave, lane);
    }
    __builtin_amdgcn_s_barrier();
    __builtin_amdgcn_s_setprio(1);
#pragma unroll
    for (int s = 0; s < 2; ++s)
#pragma unroll
      for (int m = 0; m < 4; ++m)
#pragma unroll
        for (int n = 0; n < 2; ++n)
          acc1[m][n] = __builtin_amdgcn_mfma_f32_16x16x32_bf16(a[m][s], b[n][s],
                                                               acc1[m][n], 0, 0, 0);
    __builtin_amdgcn_s_setprio(0);
    if (t + 2 < nt)
      asm volatile("s_waitcnt vmcnt(4)" ::: "memory");
    else
      asm volatile("s_waitcnt vmcnt(0)" ::: "memory");
    __builtin_amdgcn_s_barrier();
  }

  const int fro = (lane >> 4) * 4;
#define STORE_HALF(ACC, QM)                                                      \
  _Pragma("unroll") for (int m = 0; m < 4; ++m) {                                \
    _Pragma("unroll") for (int n = 0; n < 2; ++n) {                              \
      const int row = tm * 256 + QM * 128 + wr64 + m * 16 + fro;                 \
      const int col = tn * 128 + wc32 + n * 16 + fr;                             \
      if (col < 1024) {                                                          \
        _Pragma("unroll") for (int jj = 0; jj < 4; ++jj) {                       \
          int pk = __builtin_amdgcn_cvt_pk_fp8_f32(ACC[m][n][jj],                \
                                                   ACC[m][n][jj], 0, false);     \
          qo[(size_t)(row + jj) * 1024 + col] = (uint8_t)pk;                     \
        }                                                                        \
      } else if (col < 2048) {                                                   \
        _Pragma("unroll") for (int jj = 0; jj < 4; ++jj) {                       \
          int pk = __builtin_amdgcn_cvt_pk_fp8_f32(ACC[m][n][jj],                \
                                                   ACC[m][n][jj], 0, false);     \
          ko[(size_t)(row + jj) * 1024 + (col - 1024)] = (uint8_t)pk;            \
        }                                                                        \
      } else {                                                                   \
        union { bf16_t h[4]; uint2 u; } tpk;                                     \
        _Pragma("unroll") for (int jj = 0; jj < 4; ++jj)                         \
            tpk.h[jj] = (bf16_t)ACC[m][n][jj];                                   \
        *(uint2*)&vtb[(size_t)(col - 2048) * 8192 + row] = tpk.u;                \
      }                                                                          \
    }                                                                            \
  }
  STORE_HALF(acc0, 0)
  STORE_HALF(acc1, 1)
#undef STORE_HALF
}

// ============== MX-fp8 scores GEMM, 256^2 tile, 8-wave 4-phase cadence ===========
// Round-7 form — unchanged. K accumulation order identical -> bitwise-identical S.

__device__ __forceinline__ void stage_half8(const uint8_t* g, uint8_t* lh,
                                            int wave, int lane) {
#pragma unroll
  for (int i = 0; i < 2; ++i) {
    const int ub = i * 8192 + wave * 1024;
    const int o = ub + lane * 16;
    const int row = o >> 7;
    const int col = (o & 127) ^ ((row & 7) << 4);
    __builtin_amdgcn_global_load_lds((gv_t*)(g + (size_t)row * 1024 + col),
                                     (lv_t*)(lh + ub), 16, 0, 0);
  }
}

__device__ __forceinline__ i32x8 ld_frag8h(const uint8_t* h, int r, int lane) {
  const int sw = (r & 7) << 4;
  const int kg = (lane >> 4) * 32;
  const uint8_t* b = h + r * 128;
  i32x4 lo = *(const i32x4*)(b + (kg ^ sw));
  i32x4 hi = *(const i32x4*)(b + ((kg ^ sw) ^ 16));
  i32x8 v;
  v[0] = lo[0]; v[1] = lo[1]; v[2] = lo[2]; v[3] = lo[3];
  v[4] = hi[0]; v[5] = hi[1]; v[6] = hi[2]; v[7] = hi[3];
  return v;
}

__global__ __launch_bounds__(512) void scores8p(
    const uint8_t* __restrict__ qf, const uint8_t* __restrict__ kf,
    bf16_t* __restrict__ S, float* __restrict__ partial) {
  __shared__ __align__(16) uint8_t L[2][4][16384];

  const int tid = threadIdx.x;
  const int wave = tid >> 6;
  const int lane = tid & 63;

  const int bid = blockIdx.x;
  const int x = bid & 7;
  const int j = bid >> 3;
  const int tm = (x << 2) | (j & 3);  // 0..31
  const int tn = j >> 2;              // 0..31

  const uint8_t* Ab = qf + (size_t)tm * 256 * 1024;
  const uint8_t* Bb = kf + (size_t)tn * 256 * 1024;

  const int wr64 = (wave >> 2) * 64;
  const int wc32 = (wave & 3) * 32;
  const int fr = lane & 15;
  constexpr int nt = 8;  // 1024 / 128

  f32x4 acc00[4][2], acc01[4][2], acc10[4][2], acc11[4][2];
#pragma unroll
  for (int m = 0; m < 4; ++m)
#pragma unroll
    for (int n = 0; n < 2; ++n) {
      acc00[m][n] = (f32x4){0.f, 0.f, 0.f, 0.f};
      acc01[m][n] = (f32x4){0.f, 0.f, 0.f, 0.f};
      acc10[m][n] = (f32x4){0.f, 0.f, 0.f, 0.f};
      acc11[m][n] = (f32x4){0.f, 0.f, 0.f, 0.f};
    }

  stage_half8(Ab, &L[0][0][0], wave, lane);
  stage_half8(Ab + (size_t)128 * 1024, &L[0][1][0], wave, lane);
  stage_half8(Bb, &L[0][2][0], wave, lane);
  stage_half8(Bb + (size_t)128 * 1024, &L[0][3][0], wave, lane);
  stage_half8(Ab + 128, &L[1][0][0], wave, lane);
  stage_half8(Bb + (size_t)128 * 1024 + 128, &L[1][3][0], wave, lane);
  asm volatile("s_waitcnt vmcnt(4)" ::: "memory");
  __builtin_amdgcn_s_barrier();

  i32x8 a[4], bA[2], bB[2];

#pragma unroll 1
  for (int t = 0; t < nt; ++t) {
    const int cur = t & 1;
    const uint8_t* A0h = &L[cur][0][0];
    const uint8_t* A1h = &L[cur][1][0];
    const uint8_t* B0h = &L[cur][2][0];
    const uint8_t* B1h = &L[cur][3][0];

    // -- phase 1: quadrant (0,0); stage A1(t+1)
#pragma unroll
    for (int m = 0; m < 4; ++m) a[m] = ld_frag8h(A0h, wr64 + m * 16 + fr, lane);
#pragma unroll
    for (int n = 0; n < 2; ++n) bA[n] = ld_frag8h(B0h, wc32 + n * 16 + fr, lane);
    if (t + 1 < nt)
      stage_half8(Ab + (size_t)128 * 1024 + (t + 1) * 128, &L[cur ^ 1][1][0],
                  wave, lane);
    __builtin_amdgcn_s_barrier();
    __builtin_amdgcn_s_setprio(1);
#pragma unroll
    for (int m = 0; m < 4; ++m)
#pragma unroll
      for (int n = 0; n < 2; ++n)
        acc00[m][n] = __builtin_amdgcn_mfma_scale_f32_16x16x128_f8f6f4(
            a[m], bA[n], acc00[m][n], 0, 0, 0, 0x7F7F7F7F, 0, 0x7F7F7F7F);
    __builtin_amdgcn_s_setprio(0);
    __builtin_amdgcn_s_barrier();

    // -- phase 2: quadrant (0,1); stage B0(t+1)
#pragma unroll
    for (int n = 0; n < 2; ++n) bB[n] = ld_frag8h(B1h, wc32 + n * 16 + fr, lane);
    if (t + 1 < nt)
      stage_half8(Bb + (t + 1) * 128, &L[cur ^ 1][2][0], wave, lane);
    __builtin_amdgcn_s_barrier();
    __builtin_amdgcn_s_setprio(1);
#pragma unroll
    for (int m = 0; m < 4; ++m)
#pragma unroll
      for (int n = 0; n < 2; ++n)
        acc01[m][n] = __builtin_amdgcn_mfma_scale_f32_16x16x128_f8f6f4(
            a[m], bB[n], acc01[m][n], 0, 0, 0, 0x7F7F7F7F, 0, 0x7F7F7F7F);
    __builtin_amdgcn_s_setprio(0);
    __builtin_amdgcn_s_barrier();

    // -- phase 3: quadrant (1,1); stage A0(t+2)
#pragma unroll
    for (int m = 0; m < 4; ++m) a[m] = ld_frag8h(A1h, wr64 + m * 16 + fr, lane);
    if (t + 2 < nt)
      stage_half8(Ab + (t + 2) * 128, &L[cur][0][0], wave, lane);
    __builtin_amdgcn_s_barrier();
    __builtin_amdgcn_s_setprio(1);
#pragma unroll
    for (int m = 0; m < 4; ++m)
#pragma unroll
      for (int n = 0; n < 2; ++n)
        acc11[m][n] = __builtin_amdgcn_mfma_scale_f32_16x16x128_f8f6f4(
            a[m], bB[n], acc11[m][n], 0, 0, 0, 0x7F7F7F7F, 0, 0x7F7F7F7F);
    __builtin_amdgcn_s_setprio(0);
    __builtin_amdgcn_s_barrier();

    // -- phase 4: quadrant (1,0); stage B1(t+2); boundary counted-vmcnt
    if (t + 2 < nt)
      stage_half8(Bb + (size_t)128 * 1024 + (t + 2) * 128, &L[cur][3][0],
                  wave, lane);
    __builtin_amdgcn_s_barrier();
    __builtin_amdgcn_s_setprio(1);
#pragma unroll
    for (int m = 0; m < 4; ++m)
#pragma unroll
      for (int n = 0; n < 2; ++n)
        acc10[m][n] = __builtin_amdgcn_mfma_scale_f32_16x16x128_f8f6f4(
            a[m], bA[n], acc10[m][n], 0, 0, 0, 0x7F7F7F7F, 0, 0x7F7F7F7F);
    __builtin_amdgcn_s_setprio(0);
    if (t + 2 < nt)
      asm volatile("s_waitcnt vmcnt(4)" ::: "memory");
    else
      asm volatile("s_waitcnt vmcnt(0)" ::: "memory");
    __builtin_amdgcn_s_barrier();
  }

  // Epilogue: exp, bf16 store, per-row partial sums (verified rounds 4-13).
  const int fro = (lane >> 4) * 4;
#define EXPSTORE(ACC, QM, QN)                                                    \
  _Pragma("unroll") for (int m = 0; m < 4; ++m)                                  \
  _Pragma("unroll") for (int n = 0; n < 2; ++n)                                  \
  _Pragma("unroll") for (int jj = 0; jj < 4; ++jj) {                             \
    float e = __expf(ACC[m][n][jj]);                                             \
    ACC[m][n][jj] = e;                                                           \
    const int row = tm * 256 + QM * 128 + wr64 + m * 16 + fro + jj;              \
    const int col = tn * 256 + QN * 128 + wc32 + n * 16 + fr;                    \
    S[(size_t)row * 8192 + col] = (bf16_t)e;                                     \
  }
  EXPSTORE(acc00, 0, 0)
  EXPSTORE(acc01, 0, 1)
  EXPSTORE(acc10, 1, 0)
  EXPSTORE(acc11, 1, 1)
#undef EXPSTORE
  float* lsum = (float*)&L[0][0][0];  // 4 KB, LDS dead after K-loop
#define ROWSUM(A0, A1, QM)                                                       \
  _Pragma("unroll") for (int m = 0; m < 4; ++m) {                                \
    _Pragma("unroll") for (int jj = 0; jj < 4; ++jj) {                           \
      float s = A0[m][0][jj] + A0[m][1][jj] + A1[m][0][jj] + A1[m][1][jj];       \
      s += __shfl_xor(s, 1, 64);                                                 \
      s += __shfl_xor(s, 2, 64);                                                 \
      s += __shfl_xor(s, 4, 64);                                                 \
      s += __shfl_xor(s, 8, 64);                                                 \
      if (fr == 0) {                                                             \
        const int rl = QM * 128 + wr64 + m * 16 + fro + jj;                      \
        lsum[rl * 4 + (wave & 3)] = s;                                           \
      }                                                                          \
    }                                                                            \
  }
  ROWSUM(acc00, acc01, 0)
  ROWSUM(acc10, acc11, 1)
#undef ROWSUM
  __syncthreads();
  if (tid < 256) {
    float s = lsum[tid * 4] + lsum[tid * 4 + 1] + lsum[tid * 4 + 2] +
              lsum[tid * 4 + 3];
    partial[(size_t)tn * 8192 + tm * 256 + tid] = s;
  }
}

// ======================= fused convert, add =======================
__global__ __launch_bounds__(256) void cvt_fused(const float* __restrict__ x,
                                                 const float* __restrict__ wq,
                                                 const float* __restrict__ wk,
                                                 const float* __restrict__ wv,
                                                 bf16_t* __restrict__ dst,
                                                 float sq) {
  constexpr int NX = 8192 * 1024 / 8;  // x groups of 8
  constexpr int NW = 1024 * 1024 / 8;  // each W's groups of 8
  const int i = blockIdx.x * 256 + threadIdx.x;
  const float* s;
  int k = i;
  float scale;
  if (i < NX) {
    s = x; scale = 1.0f;
  } else if (i < NX + NW) {
    s = wq; k = i - NX; scale = sq;
  } else if (i < NX + 2 * NW) {
    s = wk; k = i - NX - NW; scale = sq;
  } else {
    s = wv; k = i - NX - 2 * NW; scale = 1.0f;
  }
  const float4* sp = (const float4*)s + (size_t)k * 2;
  float4 x0 = sp[0], x1 = sp[1];
  bf16x8 o;
  o[0] = (bf16_t)(x0.x * scale);
  o[1] = (bf16_t)(x0.y * scale);
  o[2] = (bf16_t)(x0.z * scale);
  o[3] = (bf16_t)(x0.w * scale);
  o[4] = (bf16_t)(x1.x * scale);
  o[5] = (bf16_t)(x1.y * scale);
  o[6] = (bf16_t)(x1.z * scale);
  o[7] = (bf16_t)(x1.w * scale);
  ((bf16x8*)dst)[i] = o;
}

__global__ __launch_bounds__(256) void add_p1(float* __restrict__ out,
                                              const bf16_t* __restrict__ p1b) {
  size_t i = (size_t)blockIdx.x * 256 + threadIdx.x;
  bf16x8 b = ((const bf16x8*)p1b)[i];
  float4 a0 = ((const float4*)out)[i * 2];
  float4 a1 = ((const float4*)out)[i * 2 + 1];
  a0.x += (float)b[0];
  a0.y += (float)b[1];
  a0.z += (float)b[2];
  a0.w += (float)b[3];
  a1.x += (float)b[4];
  a1.y += (float)b[5];
  a1.z += (float)b[6];
  a1.w += (float)b[7];
  ((float4*)out)[i * 2] = a0;
  ((float4*)out)[i * 2 + 1] = a1;
}

extern "C" void kernel_launch(void* const* d_in, const int* in_sizes, int n_in,
                              void* d_out, int out_size, void* d_ws, size_t ws_size,
                              hipStream_t stream) {
  const int N = 8192, D = 1024;
  const float* x = (const float*)d_in[0];
  const float* Wq = (const float*)d_in[1];
  const float* Wk = (const float*)d_in[2];
  const float* Wv = (const float*)d_in[3];
  float* out = (float*)d_out;

  // Workspace layout:
  //   [0,8)    qf  fp8 [8192,1024]   } after scores: P1b bf16 [8192,1024] (16 MB)
  //   [8,16)   kf  fp8 [8192,1024]   }
  //   [16,32)  vt  bf16 [1024,8192]  (V^T)
  //   [32,160) S   bf16 [8192,8192]  (exp'd, unnormalized)
  //   [160,161) partial f32 [32][8192] (1 MB, in ws so PV reads it while
  //             writing out)
  //   xb (16 MB) + Wb (6 MB) alias the start of S (dead before S written)
  uint8_t* qf = (uint8_t*)d_ws;
  uint8_t* kf = qf + (size_t)N * D;
  bf16_t* vt = (bf16_t*)(kf + (size_t)N * D);
  bf16_t* S = vt + (size_t)N * D;
  bf16_t* xb = S;
  bf16_t* P1b = (bf16_t*)d_ws;
  float* partial = (float*)(S + (size_t)N * N);

  const float sq = 0.1767766953f;  // 1/sqrt(32); folded into both Wq and Wk

  // 1) fused fp32 -> bf16 convert (x ++ Wq ++ Wk ++ Wv -> xb ++ Wb, contiguous)
  const int ncv = (N * D + 3 * D * D) / 8;
  cvt_fused<<<ncv / 256, 256, 0, stream>>>(x, Wq, Wk, Wv, xb, sq);

  // 2) fused QKV (256x128 2-phase, 768 blocks): q,k -> fp8; v -> vt bf16 (V^T)
  gemm2p<3072, 1024, 1024><<<(N / 256) * (3 * D / 128), 512, 0, stream>>>(
      xb, xb + (size_t)N * D, qf, kf, vt);

  // 3) scores (MX-fp8, 256^2 8-phase): S = exp(q·k) + partial row sums
  scores8p<<<(N / 256) * (N / 256), 512, 0, stream>>>(qf, kf, S, partial);

  // 4) out = (S @ vt^T) * r, 16x16 4-phase split-K=2 with fused rowsum:
  //    ks0 -> out, ks1 -> P1b
  gemm8p<1024, 4096, 8192><<<(N / 256) * (D / 256) * 2, 512, 0, stream>>>(
      S, vt, out, P1b, partial);

  // 5) out += P1b
  add_p1<<<(N * D / 8) / 256, 256, 0, stream>>>(out, P1b);
}